// Round 3
// 439.526 us; speedup vs baseline: 1.0313x; 1.0313x over previous
//
#include <hip/hip_runtime.h>
#include <hip/hip_bf16.h>

#define BATCH 2048
#define IN_DIM 128
#define GRIDN 128
#define HID 256
#define DEPTH 7

typedef unsigned int u32;
typedef __attribute__((ext_vector_type(8))) short short8;
typedef __attribute__((ext_vector_type(4))) float floatx4;

// ---------------- ws layout (bytes) ----------------
// fs2: bf16, MFMA-frag-ordered: [slab:896][nhalf:2][ks:4][tt:8][l4:4][l15:16][g8:8]
#define OFF_FST   ((size_t)0)
#define SZ_FST    ((size_t)7*128*256*128*2)       // 58,720,256
#define OFF_ZT    (OFF_FST + SZ_FST)              // fp32 z_t [128][2048]
#define SZ_ZT     ((size_t)BATCH*IN_DIM*4)
#define OFF_HPRE  (OFF_ZT + SZ_ZT)                // fp32 h_pre [2048][256]
#define SZ_HPRE   ((size_t)BATCH*HID*4)
#define OFF_STATS (OFF_HPRE + SZ_HPRE)            // fp32 stats 3*[512]
#define SZ_STATS  ((size_t)3*2*HID*4)
#define OFF_KEYS  (OFF_STATS + SZ_STATS)          // u32 keys [256]
#define SZ_KEYS   ((size_t)256*4)
#define OFF_CW    (OFF_KEYS + SZ_KEYS)            // fp32 cw[7] (+pad)
#define SZ_CW     ((size_t)32)
#define OFF_Y1    (OFF_CW + SZ_CW)
#define SZ_Y      ((size_t)BATCH*HID*4)
#define OFF_Y2    (OFF_Y1 + SZ_Y)
#define OFF_Y3    (OFF_Y2 + SZ_Y)

__device__ __forceinline__ void gload_lds16(const void* g, void* l) {
  __builtin_amdgcn_global_load_lds(
      (const __attribute__((address_space(1))) u32*)g,
      (__attribute__((address_space(3))) u32*)l, 16, 0, 0);
}

__device__ __forceinline__ u32 pack2_bf16(float lo, float hi) {
  __hip_bfloat162 b2;
  b2.x = __float2bfloat16(lo);
  b2.y = __float2bfloat16(hi);
  return *reinterpret_cast<u32*>(&b2);
}

// truncating bf16x2 pack: one v_perm_b32 (lo = hi16(a), hi = hi16(b))
__device__ __forceinline__ u32 pk_trunc(float a, float b) {
  return __builtin_amdgcn_perm(__float_as_uint(b), __float_as_uint(a), 0x07060302u);
}

__device__ __forceinline__ float gelu_exact(float x) {
  return 0.5f * x * (1.0f + erff(x * 0.70710678118654752f));
}

// ---------------- prep1: per-feature min/max via monotone-key atomics + cw
__global__ void prep1_kernel(const float* __restrict__ x, u32* __restrict__ keys,
                             const float* __restrict__ depth_scores,
                             float* __restrict__ cw) {
  int t = threadIdx.x;
  int base = blockIdx.x * 256 + t;
  float mn = 1e30f, mx = -1e30f;
#pragma unroll
  for (int j = 0; j < 16; ++j) {
    float v = x[base + j * 16384];   // 16384 % 128 == 0 -> same feature i each iter
    mn = fminf(mn, v); mx = fmaxf(mx, v);
  }
  __shared__ float smn[256], smx[256];
  smn[t] = mn; smx[t] = mx;
  __syncthreads();
  if (t < 128) {
    mn = fminf(smn[t], smn[t + 128]);
    mx = fmaxf(smx[t], smx[t + 128]);
    int i = base & 127;  // == t
    atomicMax(&keys[i], 0x7FFFFFFFu - __float_as_uint(mn));
    atomicMax(&keys[128 + i], __float_as_uint(mx));
  }
  if (blockIdx.x == 0 && t == 0) {
    float m = -1e30f;
    for (int d0 = 0; d0 < DEPTH; ++d0) m = fmaxf(m, depth_scores[d0]);
    float e[DEPTH]; float sum = 0.f;
    for (int d0 = 0; d0 < DEPTH; ++d0) { e[d0] = expf(depth_scores[d0] - m); sum += e[d0]; }
    float cacc = 0.f; float cs[DEPTH];
    for (int d0 = DEPTH - 1; d0 >= 0; --d0) { cacc += e[d0] / sum; cs[d0] = cacc; }
    for (int d0 = 0; d0 < DEPTH; ++d0) cw[d0] = cs[d0];
  }
}

// ---------------- prep2: z_t[i][b] via LDS transpose (256B contiguous stores)
__global__ void prep2_kernel(const float* __restrict__ x, const u32* __restrict__ keys,
                             float* __restrict__ z_t) {
  __shared__ float lds[128 * 65];
  int t = threadIdx.x;
  int b0 = blockIdx.x * 64;
#pragma unroll
  for (int q = 0; q < 32; ++q) {
    int idx = q * 256 + t;              // [0, 8192)
    int b = idx >> 7, i = idx & 127;
    lds[i * 65 + b] = x[(size_t)(b0 + b) * IN_DIM + i];
  }
  __syncthreads();
#pragma unroll
  for (int q = 0; q < 32; ++q) {
    int idx = q * 256 + t;
    int ii = idx >> 6, bb = idx & 63;
    float mnv = __uint_as_float(0x7FFFFFFFu - keys[ii]);
    float mxv = __uint_as_float(keys[128 + ii]);
    float v = (lds[ii * 65 + bb] - mnv) * (1.0f / (mxv - mnv + 1e-6f));
    z_t[(size_t)ii * BATCH + b0 + bb] = v;
  }
}

// ---------------- fs fp32 [d,i,g,h] -> c_d*bf16, MFMA-frag-ordered fs2 ----------------
// fs2[slab][nhalf][ks][tt][l4][l15][g8]: element (h, g) with h = nhalf*128+tt*16+l15,
// g = ks*32 + l4*8 + g8. Each 1KB slot = one contiguous wave B-fragment.
__global__ void convert_kernel(const float* __restrict__ fs,
                               const float* __restrict__ cw,
                               __hip_bfloat16* __restrict__ fs2) {
  __shared__ u32 lds[256 * 33];   // [h][33] u32 rows: +1 pad
  int slab = blockIdx.x;          // d*128 + i
  int t = threadIdx.x;
  float cd = cw[slab >> 7];
  const float* src = fs + (size_t)slab * (GRIDN * HID);
  char* dstb = (char*)fs2 + (size_t)slab * 65536;

  for (int gh = 0; gh < 2; ++gh) {
    // phase 1: row h=t, read g coalesced (lanes over h), pack scaled bf16x2
    const float* s0 = src + (size_t)gh * 64 * HID + t;
#pragma unroll
    for (int g2 = 0; g2 < 32; ++g2) {
      float va = s0[(size_t)(2 * g2) * HID];
      float vb = s0[(size_t)(2 * g2 + 1) * HID];
      lds[t * 33 + g2] = pack2_bf16(cd * va, cd * vb);
    }
    __syncthreads();
    // phase 2: emit frag-ordered 16B chunks, lanes contiguous in dst
#pragma unroll
    for (int it2 = 0; it2 < 8; ++it2) {
      int task = t + it2 * 256;         // [0,2048) = 32KB of this gh-half
      int c = task >> 9;                // [0,4): nhalf*2 + ksl
      int q = task & 511;
      int nhalf = c >> 1, ksl = c & 1;
      int tt = q >> 6, l4 = (q >> 4) & 3, l15 = q & 15;
      int h = nhalf * 128 + tt * 16 + l15;
      int m = ksl * 4 + l4;             // u32-group within this gh half
      u32 a0 = lds[h * 33 + m * 4 + 0];
      u32 a1 = lds[h * 33 + m * 4 + 1];
      u32 a2 = lds[h * 33 + m * 4 + 2];
      u32 a3 = lds[h * 33 + m * 4 + 3];
      size_t off = (size_t)nhalf * 32768 + (size_t)(gh * 2 + ksl) * 8192 +
                   (size_t)tt * 1024 + l4 * 256 + l15 * 16;
      *(uint4*)(dstb + off) = make_uint4(a0, a1, a2, a3);
    }
    __syncthreads();
  }
}

// ---------------- big GEMM: h_pre += relu(z-grids) @ (c_d*fs) ----------------
// Barrier-free wave-private QUAD-buffered async pipeline (4 x 4KB sub-steps):
//   - sub-step u (u = 2*step + half, 224 total) stages 4KB (4 x 1KB
//     global_load_lds) into buf[u&3]; while consuming sub-step u, the stages
//     for u+1, u+2 (+ one z/grids group) stay IN FLIGHT -> every main-loop
//     wait is a counted s_waitcnt vmcnt(14), never a full drain. Cover per
//     stage = 3 sub-steps (~1.5k cyc) vs ~0.5k for the old 2x8KB vmcnt(0)
//     scheme; z/grids regs are parity double-buffered with 2-step prefetch.
//   - vmcnt ledger (verified by simulation): steady queue before a wait is
//     [St(2s),Zg(s),St(2s+1),St(2s+2),Zg(s+1)] = 24 loads; vmcnt(14) retires
//     exactly the group the sub-step needs. Tail peels to 14/14/4/0.
//   - A generated in registers (pk_trunc); ds_read_b128 frag reads are
//     lane-contiguous -> conflict-free; s_setprio(1) around MFMA clusters
//     (independent-phase waves regime).
// Wave tile 64Mx128N; block 256 thr = 4 waves (2m x 2n) = 128x256 tile.
// Grid: 16 mtiles x 32 K-chunks (28 slabs) = 512 blocks = 2/CU, XCD-swizzled.
#define FENCE __asm__ volatile("" ::: "memory")
#define WAITV(c) do { __builtin_amdgcn_s_waitcnt(c); FENCE; } while (0)
#define VM14 0x0F7E
#define VM4  0x0F74
#define VM0  0x0F70

__launch_bounds__(256, 2)
__global__ void gemm_kernel(const float* __restrict__ z_t,
                            const float* __restrict__ grids,
                            const __hip_bfloat16* __restrict__ fs2,
                            float* __restrict__ h_pre) {
  __shared__ __align__(16) char lds[65536];   // 4 waves x 16KB (4 x 4KB quad buf)

  int bx = blockIdx.x;
  int xcd = bx & 7;
  int t6 = bx >> 3;                 // [0,64)
  int cg = t6 >> 4;                 // [0,4)
  int jb = t6 & 15;                 // [0,16) mtile(128)
  int chunk = xcd + 8 * cg;         // [0,32); same-XCD blocks share fs2 chunk
  int slab0 = chunk * 28;

  int tid = threadIdx.x;
  int w = tid >> 6, l = tid & 63;
  int l15 = l & 15, l4 = l >> 4;
  int wm = w >> 1;                  // m-half of block tile
  int wn = w & 1;                   // nhalf
  int mbase = jb * 128 + wm * 64;
  int nbase = wn * 128;
  char* mylds = lds + w * 16384;

  floatx4 acc[4][8];
#pragma unroll
  for (int a = 0; a < 4; ++a)
#pragma unroll
    for (int b = 0; b < 8; ++b) acc[a][b] = (floatx4)0.f;

  const char* fsb = (const char*)fs2 + (size_t)slab0 * 65536 + (size_t)wn * 32768 +
                    (size_t)l * 16;

  // stage sub-step u (4KB): step = u>>1, half = u&1 -> buf[u&3]
  auto stage4 = [&](int u) {
    const char* srcb = fsb + (size_t)(u >> 3) * 65536 + (size_t)((u >> 1) & 3) * 8192 +
                       (size_t)(u & 1) * 4096;
    char* dst = mylds + (u & 3) * 4096;
#pragma unroll
    for (int j = 0; j < 4; ++j)
      gload_lds16(srcb + j * 1024, dst + j * 1024);
  };

  float4 zA, zB;                    // z regs, parity by step (even=A, odd=B)
  float4 g0A, g1A, g0B, g1B;
  auto zgload = [&](int s, float4& zv, float4& G0, float4& G1) {
    int slab = slab0 + (s >> 2);
    int iz = slab & 127;
    const float* zp = z_t + (size_t)iz * BATCH + mbase + l15;
    zv.x = zp[0]; zv.y = zp[16]; zv.z = zp[32]; zv.w = zp[48];
    const float* gp = grids + (size_t)slab * GRIDN + (s & 3) * 32 + l4 * 8;
    G0 = *(const float4*)gp;
    G1 = *(const float4*)(gp + 4);
  };

  short8 af[4];
  short8 bf[4];
  auto rdfrag = [&](const int bufIdx) {
    const char* bp = mylds + bufIdx * 4096 + l * 16;
    bf[0] = *(const short8*)(bp);
    bf[1] = *(const short8*)(bp + 1024);
    bf[2] = *(const short8*)(bp + 2048);
    bf[3] = *(const short8*)(bp + 3072);
  };
  // A fragments: relu(z - grid), truncating bf16 pack
  auto afgen = [&](const float4 zv, const float4 G0, const float4 G1) {
#pragma unroll
    for (int u = 0; u < 4; ++u) {
      float zu = (u == 0) ? zv.x : (u == 1) ? zv.y : (u == 2) ? zv.z : zv.w;
      union { uint4 q; short8 s8; } pk;
      pk.q.x = pk_trunc(fmaxf(zu - G0.x, 0.f), fmaxf(zu - G0.y, 0.f));
      pk.q.y = pk_trunc(fmaxf(zu - G0.z, 0.f), fmaxf(zu - G0.w, 0.f));
      pk.q.z = pk_trunc(fmaxf(zu - G1.x, 0.f), fmaxf(zu - G1.y, 0.f));
      pk.q.w = pk_trunc(fmaxf(zu - G1.z, 0.f), fmaxf(zu - G1.w, 0.f));
      af[u] = pk.s8;
    }
  };
  auto mfma16 = [&](const int ttBase) {
    __builtin_amdgcn_s_setprio(1);
#pragma unroll
    for (int u = 0; u < 4; ++u) {
      acc[u][ttBase + 0] = __builtin_amdgcn_mfma_f32_16x16x32_bf16(af[u], bf[0], acc[u][ttBase + 0], 0, 0, 0);
      acc[u][ttBase + 1] = __builtin_amdgcn_mfma_f32_16x16x32_bf16(af[u], bf[1], acc[u][ttBase + 1], 0, 0, 0);
      acc[u][ttBase + 2] = __builtin_amdgcn_mfma_f32_16x16x32_bf16(af[u], bf[2], acc[u][ttBase + 2], 0, 0, 0);
      acc[u][ttBase + 3] = __builtin_amdgcn_mfma_f32_16x16x32_bf16(af[u], bf[3], acc[u][ttBase + 3], 0, 0, 0);
    }
    __builtin_amdgcn_s_setprio(0);
  };

  // prologue: queue = [Zg0(6), St0(4), St1(4), St2(4), Zg1(6)] = 24 in flight
  zgload(0, zA, g0A, g1A); FENCE;
  stage4(0); stage4(1); stage4(2); FENCE;
  zgload(1, zB, g0B, g1B); FENCE;

  // main loop: steps 0..109 (pairs), every wait = vmcnt(14)
#pragma unroll 1
  for (int s = 0; s < 110; s += 2) {
    // ---- step s (even): bufs 0/1, z regs A; prefetch Zg(s+2) -> A
    WAITV(VM14);                       // retires St(2s), Zg(s)
    stage4(2 * s + 3); FENCE;          // -> buf3
    rdfrag(0);
    afgen(zA, g0A, g1A);
    mfma16(0);
    WAITV(VM14);                       // retires St(2s+1)
    stage4(2 * s + 4); FENCE;          // -> buf0
    zgload(s + 2, zA, g0A, g1A); FENCE;
    rdfrag(1);
    mfma16(4);
    // ---- step s+1 (odd): bufs 2/3, z regs B; prefetch Zg(s+3) -> B
    WAITV(VM14);                       // retires St(2s+2), Zg(s+1)
    stage4(2 * s + 5); FENCE;          // -> buf1
    rdfrag(2);
    afgen(zB, g0B, g1B);
    mfma16(0);
    WAITV(VM14);                       // retires St(2s+3)
    stage4(2 * s + 6); FENCE;          // -> buf2
    zgload(s + 3, zB, g0B, g1B); FENCE;
    rdfrag(3);
    mfma16(4);
  }

  // ---- tail: step 110 (even, bufs 0/1, z A) — stages St223 only
  WAITV(VM14);                         // retires St220, Zg110
  stage4(223); FENCE;                  // -> buf3
  rdfrag(0);
  afgen(zA, g0A, g1A);
  mfma16(0);
  WAITV(VM14);                         // retires St221 (leaves St222,Zg111,St223)
  rdfrag(1);
  mfma16(4);
  // ---- step 111 (odd, bufs 2/3, z B)
  WAITV(VM4);                          // retires St222, Zg111 (leaves St223)
  rdfrag(2);
  afgen(zB, g0B, g1B);
  mfma16(0);
  WAITV(VM0);                          // retires St223
  rdfrag(3);
  mfma16(4);

  // epilogue: atomic accumulate (C/D: col=l&15, row=(l>>4)*4+r)
  int row0 = mbase + l4 * 4;
  int col0 = nbase + l15;
#pragma unroll
  for (int u = 0; u < 4; ++u) {
#pragma unroll
    for (int tt = 0; tt < 8; ++tt) {
      int col = col0 + tt * 16;
#pragma unroll
      for (int r = 0; r < 4; ++r) {
        int row = row0 + u * 16 + r;
        atomicAdd(&h_pre[(size_t)row * HID + col], acc[u][tt][r]);
      }
    }
  }
}

// ---------------- MLP layer: Y = act(X) @ W + b, col stats of Y ----------------
template <int FIRST>
__global__ void mlp_kernel(const float* __restrict__ Xin,
                           const float* __restrict__ statsIn,
                           const float* __restrict__ gamma,
                           const float* __restrict__ beta,
                           const float* __restrict__ W,
                           const float* __restrict__ bias,
                           float* __restrict__ Yout,
                           float* __restrict__ statsOut) {
  __shared__ float Xs[4][HID];
  int br = blockIdx.x, c = threadIdx.x;
  float mean = 0.f, rstd = 1.f, gm = 1.f, bt = 0.f;
  if (!FIRST) {
    float s1 = statsIn[c], s2 = statsIn[HID + c];
    mean = s1 * (1.0f / BATCH);
    float var = s2 * (1.0f / BATCH) - mean * mean;
    rstd = rsqrtf(var + 1e-5f);
    gm = gamma[c]; bt = beta[c];
  }
#pragma unroll
  for (int r = 0; r < 4; ++r) {
    float v = Xin[(size_t)(br * 4 + r) * HID + c];
    if (!FIRST) v = gelu_exact((v - mean) * rstd * gm + bt);
    Xs[r][c] = v;
  }
  __syncthreads();
  float acc[4] = {0, 0, 0, 0};
#pragma unroll 8
  for (int k = 0; k < HID; ++k) {
    float wv = W[(size_t)k * HID + c];
#pragma unroll
    for (int r = 0; r < 4; ++r) acc[r] += Xs[r][k] * wv;
  }
  float bb = bias[c];
  float s1 = 0.f, s2 = 0.f;
#pragma unroll
  for (int r = 0; r < 4; ++r) {
    float y = acc[r] + bb;
    Yout[(size_t)(br * 4 + r) * HID + c] = y;
    s1 += y; s2 += y * y;
  }
  atomicAdd(&statsOut[c], s1);
  atomicAdd(&statsOut[HID + c], s2);
}

// ---------------- final: out = gelu(bn(Y3)) @ W_out + b_out ----------------
__global__ void final_kernel(const float* __restrict__ Y3,
                             const float* __restrict__ statsIn,
                             const float* __restrict__ gamma,
                             const float* __restrict__ beta,
                             const float* __restrict__ W_out,
                             const float* __restrict__ b_out,
                             float* __restrict__ out) {
  int w = threadIdx.x >> 6, l = threadIdx.x & 63;
  int b = blockIdx.x * 4 + w;
  float4 y = *(const float4*)(Y3 + (size_t)b * HID + l * 4);
  float4 wv = *(const float4*)(W_out + l * 4);
  float r4[4] = {y.x, y.y, y.z, y.w};
  float w4[4] = {wv.x, wv.y, wv.z, wv.w};
  float s = 0.f;
  int c0 = l * 4;
#pragma unroll
  for (int q = 0; q < 4; ++q) {
    int c = c0 + q;
    float s1 = statsIn[c], s2 = statsIn[HID + c];
    float mean = s1 * (1.0f / BATCH);
    float var = s2 * (1.0f / BATCH) - mean * mean;
    float rstd = rsqrtf(var + 1e-5f);
    float v = gelu_exact((r4[q] - mean) * rstd * gamma[c] + beta[c]);
    s += v * w4[q];
  }
#pragma unroll
  for (int off = 32; off > 0; off >>= 1) s += __shfl_down(s, off);
  if (l == 0) out[b] = s + b_out[0];
}

extern "C" void kernel_launch(void* const* d_in, const int* in_sizes, int n_in,
                              void* d_out, int out_size, void* d_ws, size_t ws_size,
                              hipStream_t stream) {
  const float* x      = (const float*)d_in[0];
  const float* grids  = (const float*)d_in[1];
  const float* fs     = (const float*)d_in[2];
  const float* dscore = (const float*)d_in[3];
  const float* mlp_W  = (const float*)d_in[4];
  const float* mlp_b  = (const float*)d_in[5];
  const float* bn_g   = (const float*)d_in[6];
  const float* bn_b   = (const float*)d_in[7];
  const float* W_out  = (const float*)d_in[8];
  const float* b_out  = (const float*)d_in[9];
  float* out = (float*)d_out;

  char* ws = (char*)d_ws;
  __hip_bfloat16* fs2 = (__hip_bfloat16*)(ws + OFF_FST);
  float* z_t   = (float*)(ws + OFF_ZT);
  float* h_pre = (float*)(ws + OFF_HPRE);
  float* stats = (float*)(ws + OFF_STATS);
  u32*   keys  = (u32*)(ws + OFF_KEYS);
  float* cw    = (float*)(ws + OFF_CW);
  float* Y1    = (float*)(ws + OFF_Y1);
  float* Y2    = (float*)(ws + OFF_Y2);
  float* Y3    = (float*)(ws + OFF_Y3);

  // zero the atomic accumulators (h_pre + BN stats + minmax keys)
  hipMemsetAsync(h_pre, 0, SZ_HPRE + SZ_STATS + SZ_KEYS, stream);

  prep1_kernel<<<64, 256, 0, stream>>>(x, keys, dscore, cw);
  prep2_kernel<<<32, 256, 0, stream>>>(x, keys, z_t);
  convert_kernel<<<DEPTH * IN_DIM, 256, 0, stream>>>(fs, cw, fs2);
  gemm_kernel<<<512, 256, 0, stream>>>(z_t, grids, fs2, h_pre);

  mlp_kernel<1><<<512, 256, 0, stream>>>(h_pre, nullptr, nullptr, nullptr,
                                         mlp_W, mlp_b, Y1, stats);
  mlp_kernel<0><<<512, 256, 0, stream>>>(Y1, stats, bn_g, bn_b,
                                         mlp_W + 65536, mlp_b + 256, Y2, stats + 512);
  mlp_kernel<0><<<512, 256, 0, stream>>>(Y2, stats + 512, bn_g + 256, bn_b + 256,
                                         mlp_W + 2 * 65536, mlp_b + 2 * 256, Y3, stats + 1024);
  final_kernel<<<512, 256, 0, stream>>>(Y3, stats + 1024, bn_g + 512, bn_b + 512,
                                        W_out, b_out, out);
}

// Round 4
// 428.995 us; speedup vs baseline: 1.0566x; 1.0245x over previous
//
#include <hip/hip_runtime.h>
#include <hip/hip_bf16.h>

#define BATCH 2048
#define IN_DIM 128
#define GRIDN 128
#define HID 256
#define DEPTH 7

typedef unsigned int u32;
typedef __attribute__((ext_vector_type(8))) short short8;
typedef __attribute__((ext_vector_type(4))) float floatx4;

// ---------------- ws layout (bytes) ----------------
// fs2: bf16, MFMA-frag-ordered: [slab:896][nhalf:2][ks:4][tt:8][l4:4][l15:16][g8:8]
#define OFF_FST   ((size_t)0)
#define SZ_FST    ((size_t)7*128*256*128*2)       // 58,720,256
#define OFF_ZT    (OFF_FST + SZ_FST)              // fp32 z_t [128][2048]
#define SZ_ZT     ((size_t)BATCH*IN_DIM*4)
#define OFF_HPRE  (OFF_ZT + SZ_ZT)                // fp32 h_pre [2048][256]
#define SZ_HPRE   ((size_t)BATCH*HID*4)
#define OFF_STATS (OFF_HPRE + SZ_HPRE)            // fp32 stats 3*[512]
#define SZ_STATS  ((size_t)3*2*HID*4)
#define OFF_KEYS  (OFF_STATS + SZ_STATS)          // u32 keys [256]
#define SZ_KEYS   ((size_t)256*4)
#define OFF_CW    (OFF_KEYS + SZ_KEYS)            // fp32 cw[7] (+pad)
#define SZ_CW     ((size_t)32)
#define OFF_Y1    (OFF_CW + SZ_CW)
#define SZ_Y      ((size_t)BATCH*HID*4)
#define OFF_Y2    (OFF_Y1 + SZ_Y)
#define OFF_Y3    (OFF_Y2 + SZ_Y)

__device__ __forceinline__ void gload_lds16(const void* g, void* l) {
  __builtin_amdgcn_global_load_lds(
      (const __attribute__((address_space(1))) u32*)g,
      (__attribute__((address_space(3))) u32*)l, 16, 0, 0);
}

__device__ __forceinline__ u32 pack2_bf16(float lo, float hi) {
  __hip_bfloat162 b2;
  b2.x = __float2bfloat16(lo);
  b2.y = __float2bfloat16(hi);
  return *reinterpret_cast<u32*>(&b2);
}

// truncating bf16x2 pack: one v_perm_b32 (lo = hi16(a), hi = hi16(b))
__device__ __forceinline__ u32 pk_trunc(float a, float b) {
  return __builtin_amdgcn_perm(__float_as_uint(b), __float_as_uint(a), 0x07060302u);
}

// relu(v) for v in (-1,1): med3(v,0,1) == clamp -> folds into v_sub_f32 clamp
__device__ __forceinline__ float reluc(float v) {
  return __builtin_amdgcn_fmed3f(v, 0.0f, 1.0f);
}

__device__ __forceinline__ float gelu_exact(float x) {
  return 0.5f * x * (1.0f + erff(x * 0.70710678118654752f));
}

// ---------------- prep1: per-feature min/max via monotone-key atomics + cw
__global__ void prep1_kernel(const float* __restrict__ x, u32* __restrict__ keys,
                             const float* __restrict__ depth_scores,
                             float* __restrict__ cw) {
  int t = threadIdx.x;
  int base = blockIdx.x * 256 + t;
  float mn = 1e30f, mx = -1e30f;
#pragma unroll
  for (int j = 0; j < 16; ++j) {
    float v = x[base + j * 16384];   // 16384 % 128 == 0 -> same feature i each iter
    mn = fminf(mn, v); mx = fmaxf(mx, v);
  }
  __shared__ float smn[256], smx[256];
  smn[t] = mn; smx[t] = mx;
  __syncthreads();
  if (t < 128) {
    mn = fminf(smn[t], smn[t + 128]);
    mx = fmaxf(smx[t], smx[t + 128]);
    int i = base & 127;  // == t
    atomicMax(&keys[i], 0x7FFFFFFFu - __float_as_uint(mn));
    atomicMax(&keys[128 + i], __float_as_uint(mx));
  }
  if (blockIdx.x == 0 && t == 0) {
    float m = -1e30f;
    for (int d0 = 0; d0 < DEPTH; ++d0) m = fmaxf(m, depth_scores[d0]);
    float e[DEPTH]; float sum = 0.f;
    for (int d0 = 0; d0 < DEPTH; ++d0) { e[d0] = expf(depth_scores[d0] - m); sum += e[d0]; }
    float cacc = 0.f; float cs[DEPTH];
    for (int d0 = DEPTH - 1; d0 >= 0; --d0) { cacc += e[d0] / sum; cs[d0] = cacc; }
    for (int d0 = 0; d0 < DEPTH; ++d0) cw[d0] = cs[d0];
  }
}

// ---------------- prep2: z_t[i][b] via LDS transpose (256B contiguous stores)
__global__ void prep2_kernel(const float* __restrict__ x, const u32* __restrict__ keys,
                             float* __restrict__ z_t) {
  __shared__ float lds[128 * 65];
  int t = threadIdx.x;
  int b0 = blockIdx.x * 64;
#pragma unroll
  for (int q = 0; q < 32; ++q) {
    int idx = q * 256 + t;              // [0, 8192)
    int b = idx >> 7, i = idx & 127;
    lds[i * 65 + b] = x[(size_t)(b0 + b) * IN_DIM + i];
  }
  __syncthreads();
#pragma unroll
  for (int q = 0; q < 32; ++q) {
    int idx = q * 256 + t;
    int ii = idx >> 6, bb = idx & 63;
    float mnv = __uint_as_float(0x7FFFFFFFu - keys[ii]);
    float mxv = __uint_as_float(keys[128 + ii]);
    float v = (lds[ii * 65 + bb] - mnv) * (1.0f / (mxv - mnv + 1e-6f));
    z_t[(size_t)ii * BATCH + b0 + bb] = v;
  }
}

// ---------------- fs fp32 [d,i,g,h] -> c_d*bf16, MFMA-frag-ordered fs2 ----------------
// fs2[slab][nhalf][ks][tt][l4][l15][g8]: element (h, g) with h = nhalf*128+tt*16+l15,
// g = ks*32 + l4*8 + g8. Each 1KB slot = one contiguous wave B-fragment.
__global__ void convert_kernel(const float* __restrict__ fs,
                               const float* __restrict__ cw,
                               __hip_bfloat16* __restrict__ fs2) {
  __shared__ u32 lds[256 * 33];   // [h][33] u32 rows: +1 pad
  int slab = blockIdx.x;          // d*128 + i
  int t = threadIdx.x;
  float cd = cw[slab >> 7];
  const float* src = fs + (size_t)slab * (GRIDN * HID);
  char* dstb = (char*)fs2 + (size_t)slab * 65536;

  for (int gh = 0; gh < 2; ++gh) {
    // phase 1: row h=t, read g coalesced (lanes over h), pack scaled bf16x2
    const float* s0 = src + (size_t)gh * 64 * HID + t;
#pragma unroll
    for (int g2 = 0; g2 < 32; ++g2) {
      float va = s0[(size_t)(2 * g2) * HID];
      float vb = s0[(size_t)(2 * g2 + 1) * HID];
      lds[t * 33 + g2] = pack2_bf16(cd * va, cd * vb);
    }
    __syncthreads();
    // phase 2: emit frag-ordered 16B chunks, lanes contiguous in dst
#pragma unroll
    for (int it2 = 0; it2 < 8; ++it2) {
      int task = t + it2 * 256;         // [0,2048) = 32KB of this gh-half
      int c = task >> 9;                // [0,4): nhalf*2 + ksl
      int q = task & 511;
      int nhalf = c >> 1, ksl = c & 1;
      int tt = q >> 6, l4 = (q >> 4) & 3, l15 = q & 15;
      int h = nhalf * 128 + tt * 16 + l15;
      int m = ksl * 4 + l4;             // u32-group within this gh half
      u32 a0 = lds[h * 33 + m * 4 + 0];
      u32 a1 = lds[h * 33 + m * 4 + 1];
      u32 a2 = lds[h * 33 + m * 4 + 2];
      u32 a3 = lds[h * 33 + m * 4 + 3];
      size_t off = (size_t)nhalf * 32768 + (size_t)(gh * 2 + ksl) * 8192 +
                   (size_t)tt * 1024 + l4 * 256 + l15 * 16;
      *(uint4*)(dstb + off) = make_uint4(a0, a1, a2, a3);
    }
    __syncthreads();
  }
}

// ---------------- big GEMM: h_pre += relu(z-grids) @ (c_d*fs) ----------------
// SHARED-staging quad-buffered async pipeline (4 x 4KB bufs, ONE copy/block):
//   - Block = 4 waves covering DISTINCT 64-row M-strips of ONE 128-col N-half
//     (grid: 8 mtiles x 2 nhalves x 32 chunks = 512). All waves consume the
//     same B-fragments, so each wave stages only a 1KB slice per sub-step
//     (VMEM 8->2 loads/step/wave, LDS writes /4, L2 reads /2 vs wave-private).
//   - Sync: per sub-step, each wave waits its OWN counted vmcnt(8) (slice of
//     buf u landed; queue = [St 1, Zg 6, St 1, St 1, Zg 6] = 15) then raw
//     s_barrier -> all slices in + all prior-buf reads done -> safe to stage
//     buf (u+3) (overwrites buf u-1) and read buf u. Tail waits 8/8/1/0.
//   - A fragments in-register: v_sub_f32+clamp (med3(z-g,0,1) == relu since
//     z<1, g>=0 -> z-g in (-1,1)), truncating bf16 pack; s_setprio around
//     MFMA clusters.
// Wave tile 64Mx128N; block tile 256Mx128N; 2 blocks/CU (reg-bound).
#define FENCE __asm__ volatile("" ::: "memory")
#define WAITV(c) do { __builtin_amdgcn_s_waitcnt(c); FENCE; } while (0)
#define BARR do { FENCE; __builtin_amdgcn_s_barrier(); FENCE; } while (0)
#define VM8 0x0F78
#define VM1 0x0F71
#define VM0 0x0F70

__launch_bounds__(256, 2)
__global__ void gemm_kernel(const float* __restrict__ z_t,
                            const float* __restrict__ grids,
                            const __hip_bfloat16* __restrict__ fs2,
                            float* __restrict__ h_pre) {
  __shared__ __align__(16) char lds[16384];   // shared 4 x 4KB quad buffer

  int bx = blockIdx.x;
  int xcd = bx & 7;
  int t6 = bx >> 3;                 // [0,64)
  int cg = t6 >> 4;                 // [0,4)
  int jb2 = t6 & 15;                // [0,16): mtile(256) * nhalf
  int chunk = xcd + 8 * cg;         // [0,32); same-XCD blocks share fs2 chunk
  int slab0 = chunk * 28;
  int mt = jb2 >> 1;                // [0,8) 256-row mtile
  int nh = jb2 & 1;                 // n-half of output

  int tid = threadIdx.x;
  int w = tid >> 6, l = tid & 63;
  int l15 = l & 15, l4 = l >> 4;
  int mbase = mt * 256 + w * 64;    // each wave: distinct 64-row strip
  int nbase = nh * 128;

  floatx4 acc[4][8];
#pragma unroll
  for (int a = 0; a < 4; ++a)
#pragma unroll
    for (int b = 0; b < 8; ++b) acc[a][b] = (floatx4)0.f;

  // this wave's 1KB staging slice within each 4KB buf slot
  const char* fsb = (const char*)fs2 + (size_t)slab0 * 65536 + (size_t)nh * 32768 +
                    (size_t)w * 1024 + (size_t)l * 16;

  // stage slice of sub-step u (1KB): step = u>>1, half = u&1 -> buf[u&3]
  auto stage1 = [&](int u) {
    const char* srcb = fsb + (size_t)(u >> 3) * 65536 + (size_t)((u >> 1) & 3) * 8192 +
                       (size_t)(u & 1) * 4096;
    gload_lds16(srcb, lds + (u & 3) * 4096 + w * 1024);
  };

  float4 zA, zB;                    // z regs, parity by step (even=A, odd=B)
  float4 g0A, g1A, g0B, g1B;
  auto zgload = [&](int s, float4& zv, float4& G0, float4& G1) {
    int slab = slab0 + (s >> 2);
    int iz = slab & 127;
    const float* zp = z_t + (size_t)iz * BATCH + mbase + l15;
    zv.x = zp[0]; zv.y = zp[16]; zv.z = zp[32]; zv.w = zp[48];
    const float* gp = grids + (size_t)slab * GRIDN + (s & 3) * 32 + l4 * 8;
    G0 = *(const float4*)gp;
    G1 = *(const float4*)(gp + 4);
  };

  short8 af[4];
  short8 bf[4];
  auto rdfrag = [&](const int bufIdx) {
    const char* bp = lds + bufIdx * 4096 + l * 16;
    bf[0] = *(const short8*)(bp);
    bf[1] = *(const short8*)(bp + 1024);
    bf[2] = *(const short8*)(bp + 2048);
    bf[3] = *(const short8*)(bp + 3072);
  };
  // A fragments: relu(z - grid) via sub+clamp, truncating bf16 pack
  auto afgen = [&](const float4 zv, const float4 G0, const float4 G1) {
#pragma unroll
    for (int u = 0; u < 4; ++u) {
      float zu = (u == 0) ? zv.x : (u == 1) ? zv.y : (u == 2) ? zv.z : zv.w;
      union { uint4 q; short8 s8; } pk;
      pk.q.x = pk_trunc(reluc(zu - G0.x), reluc(zu - G0.y));
      pk.q.y = pk_trunc(reluc(zu - G0.z), reluc(zu - G0.w));
      pk.q.z = pk_trunc(reluc(zu - G1.x), reluc(zu - G1.y));
      pk.q.w = pk_trunc(reluc(zu - G1.z), reluc(zu - G1.w));
      af[u] = pk.s8;
    }
  };
  auto mfma16 = [&](const int ttBase) {
    __builtin_amdgcn_s_setprio(1);
#pragma unroll
    for (int u = 0; u < 4; ++u) {
      acc[u][ttBase + 0] = __builtin_amdgcn_mfma_f32_16x16x32_bf16(af[u], bf[0], acc[u][ttBase + 0], 0, 0, 0);
      acc[u][ttBase + 1] = __builtin_amdgcn_mfma_f32_16x16x32_bf16(af[u], bf[1], acc[u][ttBase + 1], 0, 0, 0);
      acc[u][ttBase + 2] = __builtin_amdgcn_mfma_f32_16x16x32_bf16(af[u], bf[2], acc[u][ttBase + 2], 0, 0, 0);
      acc[u][ttBase + 3] = __builtin_amdgcn_mfma_f32_16x16x32_bf16(af[u], bf[3], acc[u][ttBase + 3], 0, 0, 0);
    }
    __builtin_amdgcn_s_setprio(0);
  };

  // prologue: queue = [Zg0(6), St0(1), St1(1), St2(1), Zg1(6)] = 15 in flight
  zgload(0, zA, g0A, g1A); FENCE;
  stage1(0); stage1(1); stage1(2); FENCE;
  zgload(1, zB, g0B, g1B); FENCE;

  // main loop: steps 0..109 (pairs); every wait = vmcnt(8) + barrier
#pragma unroll 1
  for (int s = 0; s < 110; s += 2) {
    // ---- step s (even): bufs 0/1, z regs A; prefetch Zg(s+2) -> A
    WAITV(VM8); BARR;                  // retires St(2s), Zg(s); buf0 complete
    stage1(2 * s + 3); FENCE;          // -> buf3 (all read buf2 last sub-step)
    afgen(zA, g0A, g1A);
    rdfrag(0);
    mfma16(0);
    WAITV(VM8); BARR;                  // retires St(2s+1); buf1 complete
    stage1(2 * s + 4); FENCE;          // -> buf0
    zgload(s + 2, zA, g0A, g1A); FENCE;
    rdfrag(1);
    mfma16(4);
    // ---- step s+1 (odd): bufs 2/3, z regs B; prefetch Zg(s+3) -> B
    WAITV(VM8); BARR;                  // retires St(2s+2), Zg(s+1)
    stage1(2 * s + 5); FENCE;          // -> buf1
    afgen(zB, g0B, g1B);
    rdfrag(2);
    mfma16(0);
    WAITV(VM8); BARR;                  // retires St(2s+3)
    stage1(2 * s + 6); FENCE;          // -> buf2
    zgload(s + 3, zB, g0B, g1B); FENCE;
    rdfrag(3);
    mfma16(4);
  }

  // ---- tail: step 110 (even, bufs 0/1, z A) — stages St223 only
  WAITV(VM8); BARR;                    // retires St220, Zg110
  stage1(223); FENCE;                  // -> buf3
  afgen(zA, g0A, g1A);
  rdfrag(0);
  mfma16(0);
  WAITV(VM8); BARR;                    // retires St221 (leaves St222,Zg111,St223)
  rdfrag(1);
  mfma16(4);
  // ---- step 111 (odd, bufs 2/3, z B)
  WAITV(VM1); BARR;                    // retires St222, Zg111 (leaves St223)
  afgen(zB, g0B, g1B);
  rdfrag(2);
  mfma16(0);
  WAITV(VM0); BARR;                    // retires St223
  rdfrag(3);
  mfma16(4);

  // epilogue: atomic accumulate (C/D: col=l&15, row=(l>>4)*4+r)
  int row0 = mbase + l4 * 4;
  int col0 = nbase + l15;
#pragma unroll
  for (int u = 0; u < 4; ++u) {
#pragma unroll
    for (int tt = 0; tt < 8; ++tt) {
      int col = col0 + tt * 16;
#pragma unroll
      for (int r = 0; r < 4; ++r) {
        int row = row0 + u * 16 + r;
        atomicAdd(&h_pre[(size_t)row * HID + col], acc[u][tt][r]);
      }
    }
  }
}

// ---------------- MLP layer: Y = act(X) @ W + b, col stats of Y ----------------
template <int FIRST>
__global__ void mlp_kernel(const float* __restrict__ Xin,
                           const float* __restrict__ statsIn,
                           const float* __restrict__ gamma,
                           const float* __restrict__ beta,
                           const float* __restrict__ W,
                           const float* __restrict__ bias,
                           float* __restrict__ Yout,
                           float* __restrict__ statsOut) {
  __shared__ float Xs[4][HID];
  int br = blockIdx.x, c = threadIdx.x;
  float mean = 0.f, rstd = 1.f, gm = 1.f, bt = 0.f;
  if (!FIRST) {
    float s1 = statsIn[c], s2 = statsIn[HID + c];
    mean = s1 * (1.0f / BATCH);
    float var = s2 * (1.0f / BATCH) - mean * mean;
    rstd = rsqrtf(var + 1e-5f);
    gm = gamma[c]; bt = beta[c];
  }
#pragma unroll
  for (int r = 0; r < 4; ++r) {
    float v = Xin[(size_t)(br * 4 + r) * HID + c];
    if (!FIRST) v = gelu_exact((v - mean) * rstd * gm + bt);
    Xs[r][c] = v;
  }
  __syncthreads();
  float acc[4] = {0, 0, 0, 0};
#pragma unroll 8
  for (int k = 0; k < HID; ++k) {
    float wv = W[(size_t)k * HID + c];
#pragma unroll
    for (int r = 0; r < 4; ++r) acc[r] += Xs[r][k] * wv;
  }
  float bb = bias[c];
  float s1 = 0.f, s2 = 0.f;
#pragma unroll
  for (int r = 0; r < 4; ++r) {
    float y = acc[r] + bb;
    Yout[(size_t)(br * 4 + r) * HID + c] = y;
    s1 += y; s2 += y * y;
  }
  atomicAdd(&statsOut[c], s1);
  atomicAdd(&statsOut[HID + c], s2);
}

// ---------------- final: out = gelu(bn(Y3)) @ W_out + b_out ----------------
__global__ void final_kernel(const float* __restrict__ Y3,
                             const float* __restrict__ statsIn,
                             const float* __restrict__ gamma,
                             const float* __restrict__ beta,
                             const float* __restrict__ W_out,
                             const float* __restrict__ b_out,
                             float* __restrict__ out) {
  int w = threadIdx.x >> 6, l = threadIdx.x & 63;
  int b = blockIdx.x * 4 + w;
  float4 y = *(const float4*)(Y3 + (size_t)b * HID + l * 4);
  float4 wv = *(const float4*)(W_out + l * 4);
  float r4[4] = {y.x, y.y, y.z, y.w};
  float w4[4] = {wv.x, wv.y, wv.z, wv.w};
  float s = 0.f;
  int c0 = l * 4;
#pragma unroll
  for (int q = 0; q < 4; ++q) {
    int c = c0 + q;
    float s1 = statsIn[c], s2 = statsIn[HID + c];
    float mean = s1 * (1.0f / BATCH);
    float var = s2 * (1.0f / BATCH) - mean * mean;
    float rstd = rsqrtf(var + 1e-5f);
    float v = gelu_exact((r4[q] - mean) * rstd * gamma[c] + beta[c]);
    s += v * w4[q];
  }
#pragma unroll
  for (int off = 32; off > 0; off >>= 1) s += __shfl_down(s, off);
  if (l == 0) out[b] = s + b_out[0];
}

extern "C" void kernel_launch(void* const* d_in, const int* in_sizes, int n_in,
                              void* d_out, int out_size, void* d_ws, size_t ws_size,
                              hipStream_t stream) {
  const float* x      = (const float*)d_in[0];
  const float* grids  = (const float*)d_in[1];
  const float* fs     = (const float*)d_in[2];
  const float* dscore = (const float*)d_in[3];
  const float* mlp_W  = (const float*)d_in[4];
  const float* mlp_b  = (const float*)d_in[5];
  const float* bn_g   = (const float*)d_in[6];
  const float* bn_b   = (const float*)d_in[7];
  const float* W_out  = (const float*)d_in[8];
  const float* b_out  = (const float*)d_in[9];
  float* out = (float*)d_out;

  char* ws = (char*)d_ws;
  __hip_bfloat16* fs2 = (__hip_bfloat16*)(ws + OFF_FST);
  float* z_t   = (float*)(ws + OFF_ZT);
  float* h_pre = (float*)(ws + OFF_HPRE);
  float* stats = (float*)(ws + OFF_STATS);
  u32*   keys  = (u32*)(ws + OFF_KEYS);
  float* cw    = (float*)(ws + OFF_CW);
  float* Y1    = (float*)(ws + OFF_Y1);
  float* Y2    = (float*)(ws + OFF_Y2);
  float* Y3    = (float*)(ws + OFF_Y3);

  // zero the atomic accumulators (h_pre + BN stats + minmax keys)
  hipMemsetAsync(h_pre, 0, SZ_HPRE + SZ_STATS + SZ_KEYS, stream);

  prep1_kernel<<<64, 256, 0, stream>>>(x, keys, dscore, cw);
  prep2_kernel<<<32, 256, 0, stream>>>(x, keys, z_t);
  convert_kernel<<<DEPTH * IN_DIM, 256, 0, stream>>>(fs, cw, fs2);
  gemm_kernel<<<512, 256, 0, stream>>>(z_t, grids, fs2, h_pre);

  mlp_kernel<1><<<512, 256, 0, stream>>>(h_pre, nullptr, nullptr, nullptr,
                                         mlp_W, mlp_b, Y1, stats);
  mlp_kernel<0><<<512, 256, 0, stream>>>(Y1, stats, bn_g, bn_b,
                                         mlp_W + 65536, mlp_b + 256, Y2, stats + 512);
  mlp_kernel<0><<<512, 256, 0, stream>>>(Y2, stats + 512, bn_g + 256, bn_b + 256,
                                         mlp_W + 2 * 65536, mlp_b + 2 * 256, Y3, stats + 1024);
  final_kernel<<<512, 256, 0, stream>>>(Y3, stats + 1024, bn_g + 512, bn_b + 512,
                                        W_out, b_out, out);
}

// Round 5
// 427.546 us; speedup vs baseline: 1.0602x; 1.0034x over previous
//
#include <hip/hip_runtime.h>
#include <hip/hip_bf16.h>

#define BATCH 2048
#define IN_DIM 128
#define GRIDN 128
#define HID 256
#define DEPTH 7

typedef unsigned int u32;
typedef __attribute__((ext_vector_type(8))) short short8;
typedef __attribute__((ext_vector_type(4))) float floatx4;

// ---------------- ws layout (bytes) ----------------
// fs2: bf16, MFMA-frag-ordered: [slab:896][nhalf:2][ks:4][tt:8][l4:4][l15:16][g8:8]
#define OFF_FST   ((size_t)0)
#define SZ_FST    ((size_t)7*128*256*128*2)       // 58,720,256
#define OFF_ZT    (OFF_FST + SZ_FST)              // fp32 z_t [128][2048]
#define SZ_ZT     ((size_t)BATCH*IN_DIM*4)
#define OFF_HPRE  (OFF_ZT + SZ_ZT)                // fp32 h_pre [2048][256]
#define SZ_HPRE   ((size_t)BATCH*HID*4)
#define OFF_STATS (OFF_HPRE + SZ_HPRE)            // fp32 stats 3*[512]
#define SZ_STATS  ((size_t)3*2*HID*4)
#define OFF_KEYS  (OFF_STATS + SZ_STATS)          // u32 keys [256]
#define SZ_KEYS   ((size_t)256*4)
#define OFF_CW    (OFF_KEYS + SZ_KEYS)            // fp32 cw[7] (+pad)
#define SZ_CW     ((size_t)32)
#define OFF_Y1    (OFF_CW + SZ_CW)
#define SZ_Y      ((size_t)BATCH*HID*4)
#define OFF_Y2    (OFF_Y1 + SZ_Y)
#define OFF_Y3    (OFF_Y2 + SZ_Y)

__device__ __forceinline__ void gload_lds16(const void* g, void* l) {
  __builtin_amdgcn_global_load_lds(
      (const __attribute__((address_space(1))) u32*)g,
      (__attribute__((address_space(3))) u32*)l, 16, 0, 0);
}

__device__ __forceinline__ u32 pack2_bf16(float lo, float hi) {
  __hip_bfloat162 b2;
  b2.x = __float2bfloat16(lo);
  b2.y = __float2bfloat16(hi);
  return *reinterpret_cast<u32*>(&b2);
}

// truncating bf16x2 pack: one v_perm_b32 (lo = hi16(a), hi = hi16(b))
__device__ __forceinline__ u32 pk_trunc(float a, float b) {
  return __builtin_amdgcn_perm(__float_as_uint(b), __float_as_uint(a), 0x07060302u);
}

// relu(v) for v in (-1,1): med3(v,0,1) == clamp -> folds into v_sub_f32 clamp
__device__ __forceinline__ float reluc(float v) {
  return __builtin_amdgcn_fmed3f(v, 0.0f, 1.0f);
}

__device__ __forceinline__ float gelu_exact(float x) {
  return 0.5f * x * (1.0f + erff(x * 0.70710678118654752f));
}

// ---------------- prep1: per-feature min/max via monotone-key atomics + cw
__global__ void prep1_kernel(const float* __restrict__ x, u32* __restrict__ keys,
                             const float* __restrict__ depth_scores,
                             float* __restrict__ cw) {
  int t = threadIdx.x;
  int base = blockIdx.x * 256 + t;
  float mn = 1e30f, mx = -1e30f;
#pragma unroll
  for (int j = 0; j < 16; ++j) {
    float v = x[base + j * 16384];   // 16384 % 128 == 0 -> same feature i each iter
    mn = fminf(mn, v); mx = fmaxf(mx, v);
  }
  __shared__ float smn[256], smx[256];
  smn[t] = mn; smx[t] = mx;
  __syncthreads();
  if (t < 128) {
    mn = fminf(smn[t], smn[t + 128]);
    mx = fmaxf(smx[t], smx[t + 128]);
    int i = base & 127;  // == t
    atomicMax(&keys[i], 0x7FFFFFFFu - __float_as_uint(mn));
    atomicMax(&keys[128 + i], __float_as_uint(mx));
  }
  if (blockIdx.x == 0 && t == 0) {
    float m = -1e30f;
    for (int d0 = 0; d0 < DEPTH; ++d0) m = fmaxf(m, depth_scores[d0]);
    float e[DEPTH]; float sum = 0.f;
    for (int d0 = 0; d0 < DEPTH; ++d0) { e[d0] = expf(depth_scores[d0] - m); sum += e[d0]; }
    float cacc = 0.f; float cs[DEPTH];
    for (int d0 = DEPTH - 1; d0 >= 0; --d0) { cacc += e[d0] / sum; cs[d0] = cacc; }
    for (int d0 = 0; d0 < DEPTH; ++d0) cw[d0] = cs[d0];
  }
}

// ---------------- prep2: z_t[i][b] via LDS transpose (256B contiguous stores)
__global__ void prep2_kernel(const float* __restrict__ x, const u32* __restrict__ keys,
                             float* __restrict__ z_t) {
  __shared__ float lds[128 * 65];
  int t = threadIdx.x;
  int b0 = blockIdx.x * 64;
#pragma unroll
  for (int q = 0; q < 32; ++q) {
    int idx = q * 256 + t;              // [0, 8192)
    int b = idx >> 7, i = idx & 127;
    lds[i * 65 + b] = x[(size_t)(b0 + b) * IN_DIM + i];
  }
  __syncthreads();
#pragma unroll
  for (int q = 0; q < 32; ++q) {
    int idx = q * 256 + t;
    int ii = idx >> 6, bb = idx & 63;
    float mnv = __uint_as_float(0x7FFFFFFFu - keys[ii]);
    float mxv = __uint_as_float(keys[128 + ii]);
    float v = (lds[ii * 65 + bb] - mnv) * (1.0f / (mxv - mnv + 1e-6f));
    z_t[(size_t)ii * BATCH + b0 + bb] = v;
  }
}

// ---------------- fs fp32 [d,i,g,h] -> c_d*bf16, MFMA-frag-ordered fs2 ----------------
// fs2[slab][nhalf][ks][tt][l4][l15][g8]: element (h, g) with h = nhalf*128+tt*16+l15,
// g = ks*32 + l4*8 + g8. Each 1KB slot = one contiguous wave B-fragment.
__global__ void convert_kernel(const float* __restrict__ fs,
                               const float* __restrict__ cw,
                               __hip_bfloat16* __restrict__ fs2) {
  __shared__ u32 lds[256 * 33];   // [h][33] u32 rows: +1 pad
  int slab = blockIdx.x;          // d*128 + i
  int t = threadIdx.x;
  float cd = cw[slab >> 7];
  const float* src = fs + (size_t)slab * (GRIDN * HID);
  char* dstb = (char*)fs2 + (size_t)slab * 65536;

  for (int gh = 0; gh < 2; ++gh) {
    // phase 1: row h=t, read g coalesced (lanes over h), pack scaled bf16x2
    const float* s0 = src + (size_t)gh * 64 * HID + t;
#pragma unroll
    for (int g2 = 0; g2 < 32; ++g2) {
      float va = s0[(size_t)(2 * g2) * HID];
      float vb = s0[(size_t)(2 * g2 + 1) * HID];
      lds[t * 33 + g2] = pack2_bf16(cd * va, cd * vb);
    }
    __syncthreads();
    // phase 2: emit frag-ordered 16B chunks, lanes contiguous in dst
#pragma unroll
    for (int it2 = 0; it2 < 8; ++it2) {
      int task = t + it2 * 256;         // [0,2048) = 32KB of this gh-half
      int c = task >> 9;                // [0,4): nhalf*2 + ksl
      int q = task & 511;
      int nhalf = c >> 1, ksl = c & 1;
      int tt = q >> 6, l4 = (q >> 4) & 3, l15 = q & 15;
      int h = nhalf * 128 + tt * 16 + l15;
      int m = ksl * 4 + l4;             // u32-group within this gh half
      u32 a0 = lds[h * 33 + m * 4 + 0];
      u32 a1 = lds[h * 33 + m * 4 + 1];
      u32 a2 = lds[h * 33 + m * 4 + 2];
      u32 a3 = lds[h * 33 + m * 4 + 3];
      size_t off = (size_t)nhalf * 32768 + (size_t)(gh * 2 + ksl) * 8192 +
                   (size_t)tt * 1024 + l4 * 256 + l15 * 16;
      *(uint4*)(dstb + off) = make_uint4(a0, a1, a2, a3);
    }
    __syncthreads();
  }
}

// ---------------- big GEMM: h_pre += relu(z-grids) @ (c_d*fs) ----------------
// SHARED-staging TRIPLE-buffered pipeline, ONE barrier per K-step:
//   - Block = 4 waves covering DISTINCT 64-row M-strips of ONE 128-col N-half
//     (grid: 8 mtiles x 2 nhalves x 32 chunks = 512). All waves consume the
//     same B-fragments; each wave stages a 2KB slice of the full 8KB step
//     into buf[s%3] (3 x 8KB LDS), issued 2 steps ahead.
//   - Sync: ONE counted wait + barrier per step (112 total, was 224):
//     steady queue = [St(s):2, Zg(s):6, St(s+1):2, Zg(s+1):6] = 16 ->
//     vmcnt(8) retires exactly St(s)+Zg(s); after barrier all 4 waves'
//     slices of buf[s%3] are in. Tail: vmcnt(8) at s=110, vmcnt(0) at 111.
//   - Overwrite hazard: stage(s+2)->buf[(s+2)%3], last read at step s-1,
//     protected by the barrier at top of step s.
//   - Order per step: 8x ds_read_b128 FIRST, then afgen (48 VALU hides LDS
//     latency), then 32 MFMA (setprio-wrapped). relu via sub+clamp.
// Wave tile 64Mx128N; block tile 256Mx128N; 2 blocks/CU (reg-bound).
#define FENCE __asm__ volatile("" ::: "memory")
#define WAITV(c) do { __builtin_amdgcn_s_waitcnt(c); FENCE; } while (0)
#define BARR do { FENCE; __builtin_amdgcn_s_barrier(); FENCE; } while (0)
#define VM8 0x0F78
#define VM0 0x0F70

__launch_bounds__(256, 2)
__global__ void gemm_kernel(const float* __restrict__ z_t,
                            const float* __restrict__ grids,
                            const __hip_bfloat16* __restrict__ fs2,
                            float* __restrict__ h_pre) {
  __shared__ __align__(16) char lds[24576];   // 3 x 8KB shared triple buffer

  int bx = blockIdx.x;
  int xcd = bx & 7;
  int t6 = bx >> 3;                 // [0,64)
  int cg = t6 >> 4;                 // [0,4)
  int jb2 = t6 & 15;                // [0,16): mtile(256) * nhalf
  int chunk = xcd + 8 * cg;         // [0,32); same-XCD blocks share fs2 chunk
  int slab0 = chunk * 28;
  int mt = jb2 >> 1;                // [0,8) 256-row mtile
  int nh = jb2 & 1;                 // n-half of output

  int tid = threadIdx.x;
  int w = tid >> 6, l = tid & 63;
  int l15 = l & 15, l4 = l >> 4;
  int mbase = mt * 256 + w * 64;    // each wave: distinct 64-row strip
  int nbase = nh * 128;

  floatx4 acc[4][8];
#pragma unroll
  for (int a = 0; a < 4; ++a)
#pragma unroll
    for (int b = 0; b < 8; ++b) acc[a][b] = (floatx4)0.f;

  // this wave's 2KB staging slice base (per-lane src; dest lane-offset is HW)
  const char* fsb = (const char*)fs2 + (size_t)slab0 * 65536 + (size_t)nh * 32768 +
                    (size_t)w * 2048 + (size_t)l * 16;

  // stage full step u (block: 8KB; this wave: 2KB = 2 x 1KB) -> buf[bufIdx]
  auto stage8 = [&](int u, int bufIdx) {
    const char* srcb = fsb + (size_t)(u >> 2) * 65536 + (size_t)(u & 3) * 8192;
    char* dst = lds + bufIdx * 8192 + w * 2048;
    gload_lds16(srcb, dst);
    gload_lds16(srcb + 1024, dst + 1024);
  };

  float4 zA, zB;                    // z regs, parity by step (even=A, odd=B)
  float4 g0A, g1A, g0B, g1B;
  auto zgload = [&](int s, float4& zv, float4& G0, float4& G1) {
    int slab = slab0 + (s >> 2);
    int iz = slab & 127;
    const float* zp = z_t + (size_t)iz * BATCH + mbase + l15;
    zv.x = zp[0]; zv.y = zp[16]; zv.z = zp[32]; zv.w = zp[48];
    const float* gp = grids + (size_t)slab * GRIDN + (s & 3) * 32 + l4 * 8;
    G0 = *(const float4*)gp;
    G1 = *(const float4*)(gp + 4);
  };

  short8 af[4];
  short8 bf[8];
  auto rdfrag8 = [&](int bufIdx) {
    const char* bp = lds + bufIdx * 8192 + l * 16;
#pragma unroll
    for (int tt = 0; tt < 8; ++tt)
      bf[tt] = *(const short8*)(bp + tt * 1024);
  };
  // A fragments: relu(z - grid) via sub+clamp, truncating bf16 pack
  auto afgen = [&](const float4 zv, const float4 G0, const float4 G1) {
#pragma unroll
    for (int u = 0; u < 4; ++u) {
      float zu = (u == 0) ? zv.x : (u == 1) ? zv.y : (u == 2) ? zv.z : zv.w;
      union { uint4 q; short8 s8; } pk;
      pk.q.x = pk_trunc(reluc(zu - G0.x), reluc(zu - G0.y));
      pk.q.y = pk_trunc(reluc(zu - G0.z), reluc(zu - G0.w));
      pk.q.z = pk_trunc(reluc(zu - G1.x), reluc(zu - G1.y));
      pk.q.w = pk_trunc(reluc(zu - G1.z), reluc(zu - G1.w));
      af[u] = pk.s8;
    }
  };
  auto mfma32 = [&]() {
    __builtin_amdgcn_s_setprio(1);
#pragma unroll
    for (int u = 0; u < 4; ++u)
#pragma unroll
      for (int tt = 0; tt < 8; ++tt)
        acc[u][tt] = __builtin_amdgcn_mfma_f32_16x16x32_bf16(af[u], bf[tt], acc[u][tt], 0, 0, 0);
    __builtin_amdgcn_s_setprio(0);
  };

// full step: wait own slices+zg of step S -> barrier (all waves' slices in),
// stage S+2, ds_read frags, gen A (hides LDS latency), prefetch zg(S+2), MFMA.
#define STEP_FULL(S, BUF, STBUF, ZV, G0, G1)                                   \
  do {                                                                         \
    WAITV(VM8); BARR;                                                          \
    stage8((S) + 2, (STBUF)); FENCE;                                           \
    rdfrag8(BUF);                                                              \
    afgen(ZV, G0, G1);                                                         \
    zgload((S) + 2, ZV, G0, G1); FENCE;                                        \
    mfma32();                                                                  \
  } while (0)

  // prologue: queue = [St0:2, Zg0:6, St1:2, Zg1:6] = 16 in flight
  stage8(0, 0); FENCE;
  zgload(0, zA, g0A, g1A); FENCE;
  stage8(1, 1); FENCE;
  zgload(1, zB, g0B, g1B); FENCE;

  // main loop: steps 0..107, buf = s%3, zg parity = s%2; uniform vmcnt(8)
#pragma unroll 1
  for (int s0 = 0; s0 < 108; s0 += 6) {
    STEP_FULL(s0 + 0, 0, 2, zA, g0A, g1A);
    STEP_FULL(s0 + 1, 1, 0, zB, g0B, g1B);
    STEP_FULL(s0 + 2, 2, 1, zA, g0A, g1A);
    STEP_FULL(s0 + 3, 0, 2, zB, g0B, g1B);
    STEP_FULL(s0 + 4, 1, 0, zA, g0A, g1A);
    STEP_FULL(s0 + 5, 2, 1, zB, g0B, g1B);
  }

  // ---- tail ----
  // s=108 (buf0, A): stages 110 -> buf2, zg(110) -> A
  STEP_FULL(108, 0, 2, zA, g0A, g1A);
  // s=109 (buf1, B): stages 111 -> buf0, zg(111) -> B
  STEP_FULL(109, 1, 0, zB, g0B, g1B);
  // s=110 (buf2, A): queue [St110:2,Zg110:6,St111:2,Zg111:6] -> vmcnt(8)
  WAITV(VM8); BARR;
  rdfrag8(2);
  afgen(zA, g0A, g1A);
  mfma32();
  // s=111 (buf0, B): queue [St111:2,Zg111:6] -> vmcnt(0)
  WAITV(VM0); BARR;
  rdfrag8(0);
  afgen(zB, g0B, g1B);
  mfma32();

  // epilogue: atomic accumulate (C/D: col=l&15, row=(l>>4)*4+r)
  int row0 = mbase + l4 * 4;
  int col0 = nbase + l15;
#pragma unroll
  for (int u = 0; u < 4; ++u) {
#pragma unroll
    for (int tt = 0; tt < 8; ++tt) {
      int col = col0 + tt * 16;
#pragma unroll
      for (int r = 0; r < 4; ++r) {
        int row = row0 + u * 16 + r;
        atomicAdd(&h_pre[(size_t)row * HID + col], acc[u][tt][r]);
      }
    }
  }
}

// ---------------- MLP layer: Y = act(X) @ W + b, col stats of Y ----------------
template <int FIRST>
__global__ void mlp_kernel(const float* __restrict__ Xin,
                           const float* __restrict__ statsIn,
                           const float* __restrict__ gamma,
                           const float* __restrict__ beta,
                           const float* __restrict__ W,
                           const float* __restrict__ bias,
                           float* __restrict__ Yout,
                           float* __restrict__ statsOut) {
  __shared__ float Xs[4][HID];
  int br = blockIdx.x, c = threadIdx.x;
  float mean = 0.f, rstd = 1.f, gm = 1.f, bt = 0.f;
  if (!FIRST) {
    float s1 = statsIn[c], s2 = statsIn[HID + c];
    mean = s1 * (1.0f / BATCH);
    float var = s2 * (1.0f / BATCH) - mean * mean;
    rstd = rsqrtf(var + 1e-5f);
    gm = gamma[c]; bt = beta[c];
  }
#pragma unroll
  for (int r = 0; r < 4; ++r) {
    float v = Xin[(size_t)(br * 4 + r) * HID + c];
    if (!FIRST) v = gelu_exact((v - mean) * rstd * gm + bt);
    Xs[r][c] = v;
  }
  __syncthreads();
  float acc[4] = {0, 0, 0, 0};
#pragma unroll 8
  for (int k = 0; k < HID; ++k) {
    float wv = W[(size_t)k * HID + c];
#pragma unroll
    for (int r = 0; r < 4; ++r) acc[r] += Xs[r][k] * wv;
  }
  float bb = bias[c];
  float s1 = 0.f, s2 = 0.f;
#pragma unroll
  for (int r = 0; r < 4; ++r) {
    float y = acc[r] + bb;
    Yout[(size_t)(br * 4 + r) * HID + c] = y;
    s1 += y; s2 += y * y;
  }
  atomicAdd(&statsOut[c], s1);
  atomicAdd(&statsOut[HID + c], s2);
}

// ---------------- final: out = gelu(bn(Y3)) @ W_out + b_out ----------------
__global__ void final_kernel(const float* __restrict__ Y3,
                             const float* __restrict__ statsIn,
                             const float* __restrict__ gamma,
                             const float* __restrict__ beta,
                             const float* __restrict__ W_out,
                             const float* __restrict__ b_out,
                             float* __restrict__ out) {
  int w = threadIdx.x >> 6, l = threadIdx.x & 63;
  int b = blockIdx.x * 4 + w;
  float4 y = *(const float4*)(Y3 + (size_t)b * HID + l * 4);
  float4 wv = *(const float4*)(W_out + l * 4);
  float r4[4] = {y.x, y.y, y.z, y.w};
  float w4[4] = {wv.x, wv.y, wv.z, wv.w};
  float s = 0.f;
  int c0 = l * 4;
#pragma unroll
  for (int q = 0; q < 4; ++q) {
    int c = c0 + q;
    float s1 = statsIn[c], s2 = statsIn[HID + c];
    float mean = s1 * (1.0f / BATCH);
    float var = s2 * (1.0f / BATCH) - mean * mean;
    float rstd = rsqrtf(var + 1e-5f);
    float v = gelu_exact((r4[q] - mean) * rstd * gamma[c] + beta[c]);
    s += v * w4[q];
  }
#pragma unroll
  for (int off = 32; off > 0; off >>= 1) s += __shfl_down(s, off);
  if (l == 0) out[b] = s + b_out[0];
}

extern "C" void kernel_launch(void* const* d_in, const int* in_sizes, int n_in,
                              void* d_out, int out_size, void* d_ws, size_t ws_size,
                              hipStream_t stream) {
  const float* x      = (const float*)d_in[0];
  const float* grids  = (const float*)d_in[1];
  const float* fs     = (const float*)d_in[2];
  const float* dscore = (const float*)d_in[3];
  const float* mlp_W  = (const float*)d_in[4];
  const float* mlp_b  = (const float*)d_in[5];
  const float* bn_g   = (const float*)d_in[6];
  const float* bn_b   = (const float*)d_in[7];
  const float* W_out  = (const float*)d_in[8];
  const float* b_out  = (const float*)d_in[9];
  float* out = (float*)d_out;

  char* ws = (char*)d_ws;
  __hip_bfloat16* fs2 = (__hip_bfloat16*)(ws + OFF_FST);
  float* z_t   = (float*)(ws + OFF_ZT);
  float* h_pre = (float*)(ws + OFF_HPRE);
  float* stats = (float*)(ws + OFF_STATS);
  u32*   keys  = (u32*)(ws + OFF_KEYS);
  float* cw    = (float*)(ws + OFF_CW);
  float* Y1    = (float*)(ws + OFF_Y1);
  float* Y2    = (float*)(ws + OFF_Y2);
  float* Y3    = (float*)(ws + OFF_Y3);

  // zero the atomic accumulators (h_pre + BN stats + minmax keys)
  hipMemsetAsync(h_pre, 0, SZ_HPRE + SZ_STATS + SZ_KEYS, stream);

  prep1_kernel<<<64, 256, 0, stream>>>(x, keys, dscore, cw);
  prep2_kernel<<<32, 256, 0, stream>>>(x, keys, z_t);
  convert_kernel<<<DEPTH * IN_DIM, 256, 0, stream>>>(fs, cw, fs2);
  gemm_kernel<<<512, 256, 0, stream>>>(z_t, grids, fs2, h_pre);

  mlp_kernel<1><<<512, 256, 0, stream>>>(h_pre, nullptr, nullptr, nullptr,
                                         mlp_W, mlp_b, Y1, stats);
  mlp_kernel<0><<<512, 256, 0, stream>>>(Y1, stats, bn_g, bn_b,
                                         mlp_W + 65536, mlp_b + 256, Y2, stats + 512);
  mlp_kernel<0><<<512, 256, 0, stream>>>(Y2, stats + 512, bn_g + 256, bn_b + 256,
                                         mlp_W + 2 * 65536, mlp_b + 2 * 256, Y3, stats + 1024);
  final_kernel<<<512, 256, 0, stream>>>(Y3, stats + 1024, bn_g + 512, bn_b + 512,
                                        W_out, b_out, out);
}